// Round 6
// baseline (453.583 us; speedup 1.0000x reference)
//
#include <hip/hip_runtime.h>
#include <hip/hip_bf16.h>

typedef float f32x2 __attribute__((ext_vector_type(2)));
typedef unsigned int u32;
typedef u32 u32x4 __attribute__((ext_vector_type(4)));

// ---------------------------------------------------------------------------
// Expanded bf16 tables in ws: [pl][y][x][corner k][c]  (32 ushorts = 64B per
// (pl,y,x) entry; corners k = {(y,x),(y,x1),(y1,x),(y1,x1)} pre-clamped).
// Levels (ushort offsets): sp r: 3*res*res*32 ; tp r: 3*res*100*32.
// ---------------------------------------------------------------------------
__device__ __forceinline__ int sp_off(int r) {
    return (r==0) ? 0 : (r==1) ? 24576 : (r==2) ? 122880 : 516096;
}
__device__ __forceinline__ int tp_off(int r) {
    return (r==0) ? 2088960 : (r==1) ? 2242560 : (r==2) ? 2549760 : 3164160;
}
// total: 4,392,960 ushorts = 8,785,920 bytes

// One launch expands all 8 tables: blockIdx.y = table (0..3 sp, 4..7 tp).
// (3,8,H,W) f32  ->  (3,H,W,4,8) bf16(RN)
__global__ __launch_bounds__(256) void expand_all(
    const float* __restrict__ sp0, const float* __restrict__ sp1,
    const float* __restrict__ sp2, const float* __restrict__ sp3,
    const float* __restrict__ tp0, const float* __restrict__ tp1,
    const float* __restrict__ tp2, const float* __restrict__ tp3,
    unsigned short* __restrict__ dst)
{
    int tab = blockIdx.y;
    int r = tab & 3;
    bool is_tp = tab >= 4;
    int res = 16 << r;
    int W = is_tp ? 100 : res;
    int H = res;
    int HW = H * W;
    int total = 3 * HW * 32;
    int i = blockIdx.x * 256 + threadIdx.x;
    if (i >= total) return;

    const float* src =
        (tab==0) ? sp0 : (tab==1) ? sp1 : (tab==2) ? sp2 : (tab==3) ? sp3 :
        (tab==4) ? tp0 : (tab==5) ? tp1 : (tab==6) ? tp2 : tp3;
    int off = is_tp ? tp_off(r) : sp_off(r);

    int c  = i & 7;
    int k  = (i >> 3) & 3;
    int q  = i >> 5;            // pl*HW + y*W + x
    int x  = q % W;
    int y  = (q / W) % H;
    int pl = q / HW;
    int xk = min(x + (k & 1), W - 1);
    int yk = min(y + (k >> 1), H - 1);
    float v = src[(size_t)(pl * 8 + c) * HW + (size_t)yk * W + xk];
    __hip_bfloat16 b = __float2bfloat16(v);   // round-to-nearest
    dst[off + i] = *reinterpret_cast<unsigned short*>(&b);
}

__device__ __forceinline__ float dpp_add2(float x) {
    // x += quad_perm[1,0,3,2](x); x += quad_perm[2,3,0,1](x)  -> quad sum
    x += __int_as_float(__builtin_amdgcn_mov_dpp(__float_as_int(x), 0xB1, 0xF, 0xF, true));
    x += __int_as_float(__builtin_amdgcn_mov_dpp(__float_as_int(x), 0x4E, 0xF, 0xF, true));
    return x;
}

// ---------------------------------------------------------------------------
// Main kernel: block = 384 threads = 4 points x 24 samples x 4 corners.
// tid = p*96 + s*4 + k. Lanes 4q..4q+3 load the 4 corners of one sample from
// ONE 64B line (1 TCP access/sample), weight them, quad-DPP reduce, and each
// lane stores channels {2k,2k+1} -> out + 2*global_tid (perfectly linear).
// ---------------------------------------------------------------------------
__global__ __launch_bounds__(384) void hexplane_dpp(
    const float* __restrict__ xyz, const float* __restrict__ t,
    const float* __restrict__ bounds, const unsigned short* __restrict__ tw,
    float* __restrict__ out, int N)
{
    __shared__ float coords[4][4];   // normalized xn,yn,zn,t per point

    int tid = threadIdx.x;
    int n0  = blockIdx.x * 4;

    if (tid < 16) {
        int p = tid >> 2, comp = tid & 3;
        int n = n0 + p;
        float v = 0.0f;
        if (n < N) {
            if (comp < 3) {
                float b0 = bounds[comp], b1 = bounds[3 + comp];
                v = (xyz[(size_t)n * 3 + comp] - b0) / (b1 - b0);
            } else {
                v = t[n];
            }
        }
        coords[p][comp] = v;
    }
    __syncthreads();

    int p   = tid / 96;
    int rem = tid - p * 96;
    int s   = rem >> 2;
    int k   = rem & 3;
    int g   = s >> 2;
    int r   = s & 3;
    int res = 16 << r;
    int n   = n0 + p;

    float xn = coords[p][0], yn = coords[p][1], zn = coords[p][2], tt = coords[p][3];

    int W, H, base;
    float ix, iy;
    if (g < 3) {
        W = res; H = res;
        base = sp_off(r) + g * res * res * 32;
        float fx = (g==2) ? yn : xn;
        float fy = (g==0) ? yn : zn;
        ix = fx * (float)W - 0.5f;       // align_corners = False
        iy = fy * (float)H - 0.5f;
    } else {
        int q = g - 3;
        W = 100; H = res;
        base = tp_off(r) + q * res * 100 * 32;
        float fy = (q==0) ? xn : (q==1) ? yn : zn;
        ix = tt * 99.0f;                 // align_corners = True, W=100
        iy = fy * (float)(H - 1);
    }

    ix = fminf(fmaxf(ix, 0.0f), (float)(W - 1));
    iy = fminf(fmaxf(iy, 0.0f), (float)(H - 1));
    float x0f = floorf(ix), y0f = floorf(iy);
    float wx = ix - x0f, wy = iy - y0f;
    int x0 = (int)x0f, y0 = (int)y0f;

    float wk = ((k & 1) ? wx : 1.0f - wx) * ((k & 2) ? wy : 1.0f - wy);

    const unsigned short* e = tw + base + (size_t)(y0 * W + x0) * 32 + k * 8;
    u32x4 cv = *(const u32x4*)e;

    float p0 = __uint_as_float(cv[0] << 16)         * wk;
    float p1 = __uint_as_float(cv[0] & 0xffff0000u) * wk;
    float p2 = __uint_as_float(cv[1] << 16)         * wk;
    float p3 = __uint_as_float(cv[1] & 0xffff0000u) * wk;
    float p4 = __uint_as_float(cv[2] << 16)         * wk;
    float p5 = __uint_as_float(cv[2] & 0xffff0000u) * wk;
    float p6 = __uint_as_float(cv[3] << 16)         * wk;
    float p7 = __uint_as_float(cv[3] & 0xffff0000u) * wk;

    p0 = dpp_add2(p0); p1 = dpp_add2(p1);
    p2 = dpp_add2(p2); p3 = dpp_add2(p3);
    p4 = dpp_add2(p4); p5 = dpp_add2(p5);
    p6 = dpp_add2(p6); p7 = dpp_add2(p7);

    // lane k stores channels {2k, 2k+1}
    float a0 = (k & 1) ? p2 : p0,  a1 = (k & 1) ? p3 : p1;
    float b0 = (k & 1) ? p6 : p4,  b1 = (k & 1) ? p7 : p5;
    f32x2 o;
    o[0] = (k & 2) ? b0 : a0;
    o[1] = (k & 2) ? b1 : a1;

    if (n < N) {
        size_t gidx = (size_t)blockIdx.x * 384 + tid;
        __builtin_nontemporal_store(o, (f32x2*)(out + 2 * gidx));
    }
}

extern "C" void kernel_launch(void* const* d_in, const int* in_sizes, int n_in,
                              void* d_out, int out_size, void* d_ws, size_t ws_size,
                              hipStream_t stream) {
    // setup_inputs() dict order is INTERLEAVED: xyz, t, bounds,
    // sp0, tp0, sp1, tp1, sp2, tp2, sp3, tp3
    const float* xyz    = (const float*)d_in[0];
    const float* t      = (const float*)d_in[1];
    const float* bounds = (const float*)d_in[2];
    const float* sp[4]  = { (const float*)d_in[3], (const float*)d_in[5],
                            (const float*)d_in[7], (const float*)d_in[9] };
    const float* tp[4]  = { (const float*)d_in[4], (const float*)d_in[6],
                            (const float*)d_in[8], (const float*)d_in[10] };
    float* out = (float*)d_out;

    int N = in_sizes[0] / 3;
    unsigned short* tw = (unsigned short*)d_ws;

    // expand all tables -> 4-corner 64B entries (largest table: 1,572,864
    // elements -> 6144 blocks of 256)
    expand_all<<<dim3(6144, 8), 256, 0, stream>>>(
        sp[0], sp[1], sp[2], sp[3], tp[0], tp[1], tp[2], tp[3], tw);

    int blocks = (N + 3) / 4;   // 4 points per 384-thread block
    hexplane_dpp<<<blocks, 384, 0, stream>>>(xyz, t, bounds, tw, out, N);
}

// Round 7
// 360.108 us; speedup vs baseline: 1.2596x; 1.2596x over previous
//
#include <hip/hip_runtime.h>
#include <hip/hip_bf16.h>

typedef float f32x2 __attribute__((ext_vector_type(2)));
typedef float f32x4 __attribute__((ext_vector_type(4)));
typedef unsigned int u32;
typedef u32 u32x4 __attribute__((ext_vector_type(4)));

// ---------------------------------------------------------------------------
// bf16 transposed tables in ws (ushort units), layout (3,H,W,8):
//   sp r: 3*res*res*8   tp r: 3*res*100*8    res = 16<<r
// Total 1,098,240 ushorts = 2.2 MB  -> per-XCD L2 resident.
// ---------------------------------------------------------------------------
__device__ __forceinline__ int sp_off_u(int r) {
    return (r==0) ? 0 : (r==1) ? 6144 : (r==2) ? 30720 : 129024;
}
__device__ __forceinline__ int tp_off_u(int r) {
    return (r==0) ? 522240 : (r==1) ? 560640 : (r==2) ? 637440 : 791040;
}

// (3,8,H,W) f32 -> (3,H,W,8) bf16(RN); blockIdx.y = table (0..3 sp, 4..7 tp)
__global__ __launch_bounds__(256) void conv_all(
    const float* __restrict__ sp0, const float* __restrict__ sp1,
    const float* __restrict__ sp2, const float* __restrict__ sp3,
    const float* __restrict__ tp0, const float* __restrict__ tp1,
    const float* __restrict__ tp2, const float* __restrict__ tp3,
    unsigned short* __restrict__ dst)
{
    int tab = blockIdx.y;
    int r = tab & 3;
    bool is_tp = tab >= 4;
    int res = 16 << r;
    int HW = is_tp ? res * 100 : res * res;
    int total = 3 * 8 * HW;
    int i = blockIdx.x * 256 + threadIdx.x;
    if (i >= total) return;

    const float* src =
        (tab==0) ? sp0 : (tab==1) ? sp1 : (tab==2) ? sp2 : (tab==3) ? sp3 :
        (tab==4) ? tp0 : (tab==5) ? tp1 : (tab==6) ? tp2 : tp3;
    int off = is_tp ? tp_off_u(r) : sp_off_u(r);

    int c  = i & 7;
    int q  = i >> 3;
    int hw = q % HW;
    int pl = q / HW;
    float v = src[(size_t)(pl * 8 + c) * HW + hw];
    __hip_bfloat16 b = __float2bfloat16(v);
    dst[off + i] = *reinterpret_cast<unsigned short*>(&b);
}

__device__ __forceinline__ void bf2(u32 w, float& lo, float& hi) {
    lo = __uint_as_float(w << 16);
    hi = __uint_as_float(w & 0xffff0000u);
}

// ---------------------------------------------------------------------------
// s-major main kernel: block = 768 threads = 24 s-values x 32 points.
// u = s*32 + p  -> each 32-lane half-wave gathers from ONE plane of ONE level
// (wave-local address range 4KB..786KB instead of the whole 2.2MB table).
// Output permutation (s-major compute -> point-major store) goes through an
// XOR-swizzled LDS transpose so global stores stay linear nontemporal lines.
// ---------------------------------------------------------------------------
__global__ __launch_bounds__(768) void hexplane_sm(
    const float* __restrict__ xyz, const float* __restrict__ t,
    const float* __restrict__ bounds, const unsigned short* __restrict__ tw,
    float* __restrict__ out, int N)
{
    __shared__ float coords[32][4];     // normalized xn,yn,zn,t
    __shared__ float ostage[768 * 8];   // 24 KB bounce

    int u  = threadIdx.x;
    int n0 = blockIdx.x * 32;

    if (u < 128) {
        int p = u >> 2, comp = u & 3;
        int n = n0 + p;
        float v = 0.0f;
        if (n < N) {
            if (comp < 3) {
                float b0 = bounds[comp], b1 = bounds[3 + comp];
                v = (xyz[(size_t)n * 3 + comp] - b0) / (b1 - b0);
            } else {
                v = t[n];
            }
        }
        coords[p][comp] = v;
    }
    __syncthreads();

    int s = u >> 5;          // 0..23
    int p = u & 31;          // 0..31
    int g = s >> 2;
    int r = s & 3;
    int res = 16 << r;

    float xn = coords[p][0], yn = coords[p][1], zn = coords[p][2], tt = coords[p][3];

    int W, H, base;
    float ix, iy;
    if (g < 3) {
        W = res; H = res;
        base = sp_off_u(r) + g * res * res * 8;
        float fx = (g==2) ? yn : xn;
        float fy = (g==0) ? yn : zn;
        ix = fx * (float)W - 0.5f;       // align_corners = False
        iy = fy * (float)H - 0.5f;
    } else {
        int q = g - 3;
        W = 100; H = res;
        base = tp_off_u(r) + q * res * 100 * 8;
        float fy = (q==0) ? xn : (q==1) ? yn : zn;
        ix = tt * 99.0f;                 // align_corners = True, W=100
        iy = fy * (float)(H - 1);
    }

    ix = fminf(fmaxf(ix, 0.0f), (float)(W - 1));
    iy = fminf(fmaxf(iy, 0.0f), (float)(H - 1));
    float x0f = floorf(ix), y0f = floorf(iy);
    float wx = ix - x0f, wy = iy - y0f;
    int x0 = (int)x0f, y0 = (int)y0f;
    int x1 = min(x0 + 1, W - 1), y1 = min(y0 + 1, H - 1);

    float w00 = (1.0f - wx) * (1.0f - wy);
    float w01 = wx * (1.0f - wy);
    float w10 = (1.0f - wx) * wy;
    float w11 = wx * wy;

    const unsigned short* tb = tw + base;
    u32x4 c00 = *(const u32x4*)(tb + (size_t)(y0*W + x0) * 8);
    u32x4 c01 = *(const u32x4*)(tb + (size_t)(y0*W + x1) * 8);
    u32x4 c10 = *(const u32x4*)(tb + (size_t)(y1*W + x0) * 8);
    u32x4 c11 = *(const u32x4*)(tb + (size_t)(y1*W + x1) * 8);

    // interpolate 8 channels
    float f[8];
    #pragma unroll
    for (int k = 0; k < 4; ++k) {
        float a0, a1, b0, b1, cc0, cc1, d0, d1;
        bf2(c00[k], a0, a1);
        bf2(c01[k], b0, b1);
        bf2(c10[k], cc0, cc1);
        bf2(c11[k], d0, d1);
        f[2*k]   = a0*w00 + b0*w01 + cc0*w10 + d0*w11;
        f[2*k+1] = a1*w00 + b1*w01 + cc1*w10 + d1*w11;
    }

    // bounce write: entry e = p*24+s; pair slot j stored at j^(p&3)
    {
        int e = p * 24 + s;
        int q = p & 3;
        #pragma unroll
        for (int j = 0; j < 4; ++j) {
            int jp = j ^ q;
            f32x2 w2 = { f[2*j], f[2*j+1] };
            *(f32x2*)&ostage[e * 8 + jp * 2] = w2;
        }
    }
    __syncthreads();

    // read-out: thread u covers flat floats [4u,4u+4) and [4u+3072,4u+3076)
    int e0 = u >> 1;                     // entry for first chunk (p in [0,16))
    int pe = (e0 * 683) >> 14;           // e0 / 24  (exact for e0 < 768)
    int qe = pe & 3;
    int sg = (u & 1) ^ ((qe >> 1) & 1);  // stored 16B group
    int a0 = e0 * 8 + sg * 4;

    f32x4 v0 = *(f32x4*)&ostage[a0];
    f32x4 v1 = *(f32x4*)&ostage[a0 + 3072];
    if (qe & 1) {                        // un-swap pair order within group
        f32x4 t0 = { v0[2], v0[3], v0[0], v0[1] };
        f32x4 t1 = { v1[2], v1[3], v1[0], v1[1] };
        v0 = t0; v1 = t1;
    }

    size_t total_out = (size_t)N * 192;
    size_t F0 = (size_t)n0 * 192 + (size_t)u * 4;
    size_t F1 = F0 + 3072;
    if (F0 + 4 <= total_out)
        __builtin_nontemporal_store(v0, (f32x4*)(out + F0));
    if (F1 + 4 <= total_out)
        __builtin_nontemporal_store(v1, (f32x4*)(out + F1));
}

extern "C" void kernel_launch(void* const* d_in, const int* in_sizes, int n_in,
                              void* d_out, int out_size, void* d_ws, size_t ws_size,
                              hipStream_t stream) {
    // setup_inputs() dict order is INTERLEAVED: xyz, t, bounds,
    // sp0, tp0, sp1, tp1, sp2, tp2, sp3, tp3
    const float* xyz    = (const float*)d_in[0];
    const float* t      = (const float*)d_in[1];
    const float* bounds = (const float*)d_in[2];
    const float* sp[4]  = { (const float*)d_in[3], (const float*)d_in[5],
                            (const float*)d_in[7], (const float*)d_in[9] };
    const float* tp[4]  = { (const float*)d_in[4], (const float*)d_in[6],
                            (const float*)d_in[8], (const float*)d_in[10] };
    float* out = (float*)d_out;

    int N = in_sizes[0] / 3;
    unsigned short* tw = (unsigned short*)d_ws;

    conv_all<<<dim3(1536, 8), 256, 0, stream>>>(
        sp[0], sp[1], sp[2], sp[3], tp[0], tp[1], tp[2], tp[3], tw);

    int blocks = (N + 31) / 32;   // 32 points per 768-thread block
    hexplane_sm<<<blocks, 768, 0, stream>>>(xyz, t, bounds, tw, out, N);
}